// Round 6
// baseline (25468.507 us; speedup 1.0000x reference)
//
#include <hip/hip_runtime.h>

#define Tt  512
#define Hd  1024
#define Cc  10
#define THREADS 512
#define POLL_BOUND 20000

typedef short bf16x8 __attribute__((ext_vector_type(8)));
typedef float f32x4 __attribute__((ext_vector_type(4)));
typedef unsigned u32x4 __attribute__((ext_vector_type(4)));

__device__ __forceinline__ unsigned short f2bf(float f) {
  unsigned u = __builtin_bit_cast(unsigned, f);
  u = (u + 0x7FFFu + ((u >> 16) & 1u)) >> 16;   // RTNE
  return (unsigned short)u;
}
__device__ __forceinline__ float bf2f(unsigned short s) {
  unsigned u = ((unsigned)s) << 16;
  return __builtin_bit_cast(float, u);
}
__device__ __forceinline__ float sigmf_(float z) { return 1.0f / (1.0f + __expf(-z)); }
__device__ __forceinline__ float tanhf_(float z) { return 1.0f - 2.0f / (__expf(2.0f * z) + 1.0f); }

__device__ __forceinline__ void store_u32_sc0(unsigned* p, unsigned v) {
  asm volatile("global_store_dword %0, %1, off sc0" :: "v"(p), "v"(v) : "memory");
}
__device__ __forceinline__ unsigned load_u32_plain(const unsigned* p) {
  unsigned v;
  asm volatile("global_load_dword %0, %1, off\n\ts_waitcnt vmcnt(0)"
               : "=v"(v) : "v"(p) : "memory");
  return v;
}
__device__ __forceinline__ void inv_l1() {
  asm volatile("buffer_inv" ::: "memory");
}
__device__ __forceinline__ float bperm(int byte_addr, float v) {
  int r = __builtin_amdgcn_ds_bpermute(byte_addr, __builtin_bit_cast(int, v));
  return __builtin_bit_cast(float, r);
}

__launch_bounds__(THREADS, 2)
__global__ void lstm_kernel(
    const float* __restrict__ x,
    const float* __restrict__ wgx, const float* __restrict__ wgh, const float* __restrict__ bg,
    const float* __restrict__ wix, const float* __restrict__ wih, const float* __restrict__ bi,
    const float* __restrict__ wfx, const float* __restrict__ wfh, const float* __restrict__ bfp,
    const float* __restrict__ wox, const float* __restrict__ woh, const float* __restrict__ bo,
    const float* __restrict__ wph, const float* __restrict__ bp,
    float* __restrict__ out,
    unsigned short* __restrict__ hbuf,   // [256][1024] bf16 (lives in each XCD's L2)
    unsigned* __restrict__ flags,        // [8][32] u32 per-block flags
    unsigned* __restrict__ cnt)          // [8] slot-claim counters
{
  extern __shared__ char smem[];
  char*  hls  = smem;                               // [32 rows][2048B] swizzled bf16, 64KB
  float* xls  = (float*)(smem + 65536);             // [512][32] f32, 64KB (transposed x)
  float* pbuf = (float*)(smem + 65536 + 65536);     // [32][16] f32, 2KB (projection)

  __shared__ int slot_sh;

  const int tid = threadIdx.x;
  const int l   = tid & 63;
  const int w   = tid >> 6;          // wave 0..7

  // ---- discover physical XCD; claim a slot (group = blocks sharing an L2) ----
  unsigned xcd_r;
  asm("s_getreg_b32 %0, hwreg(HW_REG_XCC_ID, 0, 4)" : "=s"(xcd_r));
  const int g = (int)(xcd_r & 7);
  if (tid == 0) {
    unsigned s = __hip_atomic_fetch_add(&cnt[g], 1u, __ATOMIC_RELAXED,
                                        __HIP_MEMORY_SCOPE_AGENT);
    slot_sh = (int)(s & 31u);   // &31: OOB guard (co-residency forces exactly 32/XCD)
  }
  __syncthreads();
  const int j   = slot_sh;
  const int r0  = g * 32;            // batch rows owned by this XCD's group
  const int hc0 = j * 32;            // h-columns owned by this block
  unsigned* gflags = flags + (g << 5);

  // ---- init: zero LDS h (h_0 = 0) ----
  {
    u32x4 z4 = {0u,0u,0u,0u};
    #pragma unroll
    for (int i = 0; i < 8; ++i) *(u32x4*)(hls + (tid + i * THREADS) * 16) = z4;
  }
  // ---- x slice -> LDS, transposed to [t][r] ----
  #pragma unroll
  for (int i = 0; i < 8; ++i) {
    int c4 = tid + i * THREADS;
    int r = c4 >> 7, t4 = (c4 & 127) * 4;
    f32x4 v = *(const f32x4*)(x + (size_t)(r0 + r) * Tt + t4);
    xls[(t4 + 0) * 32 + r] = v[0];
    xls[(t4 + 1) * 32 + r] = v[1];
    xls[(t4 + 2) * 32 + r] = v[2];
    xls[(t4 + 3) * 32 + r] = v[3];
  }

  // ---- per-lane column mapping: wave w owns h-cols [hc0+4w, hc0+4w+4) ----
  // B-frag col (l&15) = (gate q = lc>>2, c = lc&3) -> fused col q*1024 + hcol
  const int lc   = l & 15;
  const int q    = lc >> 2;
  const int c    = lc & 3;
  const int hcol = hc0 + w * 4 + c;

  // per-lane gate constants (8 regs, loaded once)
  const float wx_g = wgx[hcol], wx_i = wix[hcol], wx_f = wfx[hcol], wx_o = wox[hcol];
  const float bb_g = bg[hcol],  bb_i = bi[hcol],  bb_f = bfp[hcol], bb_o = bo[hcol];

  // ---- Wh slice -> register B-fragments (loaded ONCE) ----
  const float* whp = (q == 0) ? wgh : (q == 1) ? wih : (q == 2) ? wfh : woh;
  const int kb = ((l >> 4) & 3) * 8;
  bf16x8 bq[32];
  #pragma unroll
  for (int kc = 0; kc < 32; ++kc) {
    bf16x8 v;
    #pragma unroll
    for (int e = 0; e < 8; ++e) v[e] = (short)f2bf(whp[(kc * 32 + kb + e) * Hd + hcol]);
    bq[kc] = v;
  }

  __syncthreads();

  float cst[8];
  #pragma unroll
  for (int i = 0; i < 8; ++i) cst[i] = 0.f;
  int dead = 0;

  const int roff0 = (l & 15) * 2048;
  const int roff1 = roff0 + 16 * 2048;
  const int swz   = (l & 7) << 4;
  const int kboff = ((l >> 4) & 3) * 16;
  const int l0b   = (l & ~12) << 2;     // bpermute byte-addr base of quad

  #pragma unroll 1
  for (int t = 0; t < Tt; ++t) {
    // ---- z = h @ Wh : A from LDS (swizzled), B from registers ----
    f32x4 acc0 = {0.f,0.f,0.f,0.f};
    f32x4 acc1 = {0.f,0.f,0.f,0.f};
    #pragma unroll
    for (int kc = 0; kc < 32; ++kc) {
      int boff = (kc * 64 + kboff) ^ swz;
      bf16x8 a0 = *(const bf16x8*)(hls + roff0 + boff);
      bf16x8 a1 = *(const bf16x8*)(hls + roff1 + boff);
      acc0 = __builtin_amdgcn_mfma_f32_16x16x32_bf16(a0, bq[kc], acc0, 0, 0, 0);
      acc1 = __builtin_amdgcn_mfma_f32_16x16x32_bf16(a1, bq[kc], acc1, 0, 0, 0);
    }

    // ---- wave-local gates: gather 4 gate z's within the 16-lane quad ----
    float hv8[8];
    #pragma unroll
    for (int p = 0; p < 4; ++p) {
      #pragma unroll
      for (int hf = 0; hf < 2; ++hf) {
        float z = hf ? acc1[p] : acc0[p];
        float zg = bperm(l0b +  0, z);
        float zi = bperm(l0b + 16, z);
        float zf = bperm(l0b + 32, z);
        float zo = bperm(l0b + 48, z);
        int row = ((l >> 4) & 3) * 4 + p + hf * 16;
        float xv = xls[t * 32 + row];
        float G = tanhf_(zg + xv * wx_g + bb_g);
        float I = sigmf_(zi + xv * wx_i + bb_i);
        float F = sigmf_(zf + xv * wx_f + bb_f);
        float O = sigmf_(zo + xv * wx_o + bb_o);
        int ci = p * 2 + hf;
        float cn = G * I + cst[ci] * F;
        cst[ci] = cn;
        hv8[ci] = tanhf_(cn) * O;
      }
    }
    // ---- h' stores (q==0 lanes own the value) ----
    if (q == 0) {
      #pragma unroll
      for (int p = 0; p < 4; ++p)
        #pragma unroll
        for (int hf = 0; hf < 2; ++hf) {
          int row = ((l >> 4) & 3) * 4 + p + hf * 16;
          hbuf[(size_t)(r0 + row) * Hd + hcol] = f2bf(hv8[p * 2 + hf]);
        }
    }

    // ---- group barrier: per-block flag words, load-only polling ----
    __syncthreads();                       // sync_A: drains all waves' h' stores
    if (tid == 0) store_u32_sc0(&gflags[j], (unsigned)(t + 1));
    if (w == 0 && l < 32 && !dead) {
      const unsigned* f = &gflags[l];
      int it = 0;
      for (; it < POLL_BOUND; ++it) {
        inv_l1();
        if (load_u32_plain(f) >= (unsigned)(t + 1)) break;
        __builtin_amdgcn_s_sleep(1);
      }
      if (it >= POLL_BOUND) dead = 1;      // fail fast, never hang
    }
    __syncthreads();                       // sync_B: release all waves

    // ---- stage h_{t+1}: L1 inv + async global->LDS (swizzle on global src) ----
    inv_l1();
    {
      int rbase = w * 4;
      #pragma unroll
      for (int i = 0; i < 8; ++i) {
        int r = rbase + (i >> 1);
        int half = i & 1;
        char* ldsb = hls + r * 2048 + half * 1024;   // wave-uniform, linear dest
        int m = half * 64 + l;
        int srcc = m ^ (r & 7);                       // inverse swizzle on source
        const char* gp = (const char*)hbuf + (((size_t)(r0 + r) << 10) + srcc * 8) * 2;
        __builtin_amdgcn_global_load_lds(gp, ldsb, 16, 0, 0);
      }
    }
    __syncthreads();                       // sync_C: all staging landed
  }

  // ---- projection + softmax: slot-0 block of each XCD ----
  if (j == 0) {
    if (tid < 320) {
      int r = tid / 10;
      int cls = tid - r * 10;
      float acc = bp[cls];
      for (int k16 = 0; k16 < 128; ++k16) {
        const unsigned short* hp =
            (const unsigned short*)(hls + r * 2048 + ((k16 * 16) ^ ((r & 7) << 4)));
        #pragma unroll
        for (int e = 0; e < 8; ++e) acc += bf2f(hp[e]) * wph[(k16 * 8 + e) * Cc + cls];
      }
      pbuf[r * 16 + cls] = acc;
    }
    __syncthreads();
    if (tid < 32) {
      int r = tid;
      float m = -1e30f;
      #pragma unroll
      for (int cc = 0; cc < Cc; ++cc) m = fmaxf(m, pbuf[r * 16 + cc]);
      float s = 0.f;
      float ev[Cc];
      #pragma unroll
      for (int cc = 0; cc < Cc; ++cc) { ev[cc] = __expf(pbuf[r * 16 + cc] - m); s += ev[cc]; }
      float inv = 1.0f / s;
      #pragma unroll
      for (int cc = 0; cc < Cc; ++cc) out[(r0 + r) * Cc + cc] = ev[cc] * inv;
    }
  }
}

extern "C" void kernel_launch(void* const* d_in, const int* in_sizes, int n_in,
                              void* d_out, int out_size, void* d_ws, size_t ws_size,
                              hipStream_t stream) {
  const float* x   = (const float*)d_in[0];
  const float* wgx = (const float*)d_in[1];
  const float* wgh = (const float*)d_in[2];
  const float* bg  = (const float*)d_in[3];
  const float* wix = (const float*)d_in[4];
  const float* wih = (const float*)d_in[5];
  const float* bi  = (const float*)d_in[6];
  const float* wfx = (const float*)d_in[7];
  const float* wfh = (const float*)d_in[8];
  const float* bfp = (const float*)d_in[9];
  const float* wox = (const float*)d_in[10];
  const float* woh = (const float*)d_in[11];
  const float* bo  = (const float*)d_in[12];
  const float* wph = (const float*)d_in[13];
  const float* bp  = (const float*)d_in[14];
  float* out = (float*)d_out;

  unsigned short* hbuf = (unsigned short*)d_ws;                            // 512KB
  unsigned* flags = (unsigned*)((char*)d_ws + (size_t)256 * Hd * 2);       // 1KB
  unsigned* cnt   = (unsigned*)((char*)d_ws + (size_t)256 * Hd * 2 + 1024);

  hipMemsetAsync(flags, 0, 1024 + 64, stream);   // zero flags + slot counters

  size_t shmem = 65536 + 65536 + 2048;
  hipFuncSetAttribute((const void*)lstm_kernel,
                      hipFuncAttributeMaxDynamicSharedMemorySize, (int)shmem);

  void* args[] = {
    (void*)&x,   (void*)&wgx, (void*)&wgh, (void*)&bg,
    (void*)&wix, (void*)&wih, (void*)&bi,
    (void*)&wfx, (void*)&wfh, (void*)&bfp,
    (void*)&wox, (void*)&woh, (void*)&bo,
    (void*)&wph, (void*)&bp,
    (void*)&out, (void*)&hbuf, (void*)&flags, (void*)&cnt
  };
  hipLaunchCooperativeKernel((const void*)lstm_kernel, dim3(256), dim3(512),
                             args, (unsigned)shmem, stream);
}

// Round 7
// 8622.382 us; speedup vs baseline: 2.9538x; 2.9538x over previous
//
#include <hip/hip_runtime.h>

#define Tt  512
#define Hd  1024
#define Cc  10
#define THREADS 512
#define POLL_BOUND 30000
#define HBELT (256 * 1024)   // elements per h buffer (256 rows x 1024 cols)

typedef short bf16x8 __attribute__((ext_vector_type(8)));
typedef float f32x4 __attribute__((ext_vector_type(4)));
typedef unsigned u32x4 __attribute__((ext_vector_type(4)));

__device__ __forceinline__ unsigned short f2bf(float f) {
  unsigned u = __builtin_bit_cast(unsigned, f);
  u = (u + 0x7FFFu + ((u >> 16) & 1u)) >> 16;   // RTNE
  return (unsigned short)u;
}
__device__ __forceinline__ float bf2f(unsigned short s) {
  unsigned u = ((unsigned)s) << 16;
  return __builtin_bit_cast(float, u);
}
__device__ __forceinline__ float sigmf_(float z) { return 1.0f / (1.0f + __expf(-z)); }
__device__ __forceinline__ float tanhf_(float z) { return 1.0f - 2.0f / (__expf(2.0f * z) + 1.0f); }

__device__ __forceinline__ void store_u32_sc0(unsigned* p, unsigned v) {
  asm volatile("global_store_dword %0, %1, off sc0" :: "v"(p), "v"(v) : "memory");
}
// Atomic RMW executes at the XCD's L2 — always fresh (proven: v5 absmax 0.0).
__device__ __forceinline__ unsigned atomic_read_l2(unsigned* p) {
  unsigned old, zero = 0u;
  asm volatile("global_atomic_add %0, %1, %2, off sc0\n\ts_waitcnt vmcnt(0)"
               : "=&v"(old) : "v"(p), "v"(zero) : "memory");
  return old;
}
__device__ __forceinline__ void inv_l1() {
  asm volatile("buffer_inv" ::: "memory");
}

__launch_bounds__(THREADS, 2)
__global__ void lstm_kernel(
    const float* __restrict__ x,
    const float* __restrict__ wgx, const float* __restrict__ wgh, const float* __restrict__ bg,
    const float* __restrict__ wix, const float* __restrict__ wih, const float* __restrict__ bi,
    const float* __restrict__ wfx, const float* __restrict__ wfh, const float* __restrict__ bfp,
    const float* __restrict__ wox, const float* __restrict__ woh, const float* __restrict__ bo,
    const float* __restrict__ wph, const float* __restrict__ bp,
    float* __restrict__ out,
    unsigned short* __restrict__ hbuf,   // [2][256][1024] bf16 (double-buffered, XCD L2)
    unsigned* __restrict__ sync)         // flags[8][32][32] | epochs[8][8][32] | cnt[8]
{
  extern __shared__ char smem[];
  char*  hls  = smem;                               // [32 rows][2048B] swizzled bf16, 64KB
  float* zbuf = (float*)(smem + 65536);             // [32][128] f32, 16KB
  float* xls  = (float*)(smem + 65536 + 16384);     // [512][32] f32, 64KB (transposed x)
  float* wxb  = (float*)(smem + 65536 + 16384 + 65536);  // [4][32]
  float* bbl  = wxb + 128;                               // [4][32]

  __shared__ int slot_sh;

  const int tid = threadIdx.x;
  const int l   = tid & 63;
  const int w   = tid >> 6;          // wave 0..7

  // ---- discover physical XCD; claim a slot (group = blocks sharing an L2) ----
  unsigned xcd_r;
  asm("s_getreg_b32 %0, hwreg(HW_REG_XCC_ID, 0, 4)" : "=s"(xcd_r));
  const int g = (int)(xcd_r & 7);
  unsigned* cntp = sync + 8 * 32 * 32 + 8 * 8 * 32;
  if (tid == 0) {
    unsigned s = __hip_atomic_fetch_add(&cntp[g], 1u, __ATOMIC_RELAXED,
                                        __HIP_MEMORY_SCOPE_AGENT);
    slot_sh = (int)(s & 31u);   // &31: OOB guard (co-residency forces exactly 32/XCD)
  }
  __syncthreads();
  const int j   = slot_sh;
  const int r0  = g * 32;            // batch rows owned by this XCD's group
  const int hc0 = j * 32;            // h-columns owned by this block
  unsigned* gflag  = sync + g * (32 * 32);             // 32 lines x 128B
  unsigned* gepoch = sync + 8 * 32 * 32 + g * (8 * 32); // 8 replicated epoch lines

  // ---- init: zero LDS h (h_0 = 0) ----
  {
    u32x4 z4 = {0u,0u,0u,0u};
    #pragma unroll
    for (int i = 0; i < 8; ++i) *(u32x4*)(hls + (tid + i * THREADS) * 16) = z4;
  }
  // ---- x slice -> LDS, transposed to [t][r] ----
  #pragma unroll
  for (int i = 0; i < 8; ++i) {
    int c4 = tid + i * THREADS;
    int r = c4 >> 7, t4 = (c4 & 127) * 4;
    f32x4 v = *(const f32x4*)(x + (size_t)(r0 + r) * Tt + t4);
    xls[(t4 + 0) * 32 + r] = v[0];
    xls[(t4 + 1) * 32 + r] = v[1];
    xls[(t4 + 2) * 32 + r] = v[2];
    xls[(t4 + 3) * 32 + r] = v[3];
  }
  // ---- wx, b slices into LDS ----
  if (tid < 128) {
    int qq = tid >> 5, hcl = tid & 31;
    const float* px = (qq == 0) ? wgx : (qq == 1) ? wix : (qq == 2) ? wfx : wox;
    const float* pb = (qq == 0) ? bg  : (qq == 1) ? bi  : (qq == 2) ? bfp : bo;
    wxb[tid] = px[hc0 + hcl];
    bbl[tid] = pb[hc0 + hcl];
  }

  // ---- Wh slice -> register B-fragments (loaded ONCE) ----
  const int q = w >> 1;
  const float* whp = (q == 0) ? wgh : (q == 1) ? wih : (q == 2) ? wfh : woh;
  const int bcol = hc0 + ((w & 1) << 4) + (l & 15);
  const int kb = ((l >> 4) & 3) * 8;
  bf16x8 bq[32];
  #pragma unroll
  for (int kc = 0; kc < 32; ++kc) {
    bf16x8 v;
    #pragma unroll
    for (int e = 0; e < 8; ++e) v[e] = (short)f2bf(whp[(kc * 32 + kb + e) * Hd + bcol]);
    bq[kc] = v;
  }

  __syncthreads();

  float creg0 = 0.f, creg1 = 0.f;
  int dead = 0;

  const int roff0 = (l & 15) * 2048;
  const int roff1 = roff0 + 16 * 2048;
  const int swz   = (l & 7) << 4;
  const int kboff = ((l >> 4) & 3) * 16;

  #pragma unroll 1
  for (int t = 0; t < Tt; ++t) {
    const int p1 = (t + 1) & 1;                    // double-buffer parity
    unsigned short* hw = hbuf + (size_t)p1 * HBELT;

    // ---- z = h @ Wh : A from LDS (swizzled), B from registers ----
    f32x4 acc0 = {0.f,0.f,0.f,0.f};
    f32x4 acc1 = {0.f,0.f,0.f,0.f};
    #pragma unroll
    for (int kc = 0; kc < 32; ++kc) {
      int boff = (kc * 64 + kboff) ^ swz;
      bf16x8 a0 = *(const bf16x8*)(hls + roff0 + boff);
      bf16x8 a1 = *(const bf16x8*)(hls + roff1 + boff);
      acc0 = __builtin_amdgcn_mfma_f32_16x16x32_bf16(a0, bq[kc], acc0, 0, 0, 0);
      acc1 = __builtin_amdgcn_mfma_f32_16x16x32_bf16(a1, bq[kc], acc1, 0, 0, 0);
    }

    // ---- acc -> zbuf ----
    {
      int colz  = (w << 4) + (l & 15);
      int rbase = ((l >> 4) & 3) * 4;
      #pragma unroll
      for (int p = 0; p < 4; ++p) {
        zbuf[(rbase + p) * 128 + colz]      = acc0[p];
        zbuf[(rbase + p + 16) * 128 + colz] = acc1[p];
      }
    }
    __syncthreads();

    // ---- gates + c update (f32), h' -> hb[p1] (plain cached stores -> L2) ----
    #pragma unroll
    for (int e = 0; e < 2; ++e) {
      int idx = tid + e * THREADS;
      int r = idx >> 5, hc = idx & 31;
      float xv = xls[t * 32 + r];
      float zg = zbuf[r * 128 +       hc] + xv * wxb[      hc] + bbl[      hc];
      float zi = zbuf[r * 128 +  32 + hc] + xv * wxb[ 32 + hc] + bbl[ 32 + hc];
      float zf = zbuf[r * 128 +  64 + hc] + xv * wxb[ 64 + hc] + bbl[ 64 + hc];
      float zo = zbuf[r * 128 +  96 + hc] + xv * wxb[ 96 + hc] + bbl[ 96 + hc];
      float gg = tanhf_(zg);
      float ii = sigmf_(zi);
      float ff = sigmf_(zf);
      float oo = sigmf_(zo);
      float cold = e ? creg1 : creg0;
      float cnew = gg * ii + cold * ff;
      if (e) creg1 = cnew; else creg0 = cnew;
      float hv = tanhf_(cnew) * oo;
      hw[(size_t)(r0 + r) * Hd + hc0 + hc] = f2bf(hv);
    }

    // ---- group barrier: arrive on own line; aggregator sweeps; epoch broadcast ----
    __syncthreads();                     // drains every wave's h' stores (vmcnt0)
    if (tid == 0) store_u32_sc0(&gflag[j * 32], (unsigned)(t + 1));
    if (j == 0) {
      // aggregator: 32 lanes poll 32 DIFFERENT lines (no same-line RMW pileup)
      if (w == 0 && l < 32 && !dead) {
        unsigned* fl = &gflag[l * 32];
        int it = 0;
        while (atomic_read_l2(fl) < (unsigned)(t + 1) && it < POLL_BOUND) {
          ++it;
          __builtin_amdgcn_s_sleep(2);
        }
        if (it >= POLL_BOUND) dead = 1;
      }
      // publish epoch to 8 replicated lines (loop reconverged => all flags seen)
      if (w == 0 && l < 8) store_u32_sc0(&gepoch[l * 32], (unsigned)(t + 1));
    } else {
      if (tid == 0 && !dead) {
        unsigned* ep = &gepoch[(j & 7) * 32];   // <=4 pollers per replica
        int it = 0;
        while (atomic_read_l2(ep) < (unsigned)(t + 1) && it < POLL_BOUND) {
          ++it;
          __builtin_amdgcn_s_sleep(2);
        }
        if (it >= POLL_BOUND) dead = 1;
      }
    }
    __syncthreads();                     // release all waves

    // ---- L1 invalidate, then stage h_{t+1} from hb[p1] ----
    inv_l1();
    {
      int rbase = w * 4;
      #pragma unroll
      for (int i = 0; i < 8; ++i) {
        int r = rbase + (i >> 1);
        int half = i & 1;
        char* ldsb = hls + r * 2048 + half * 1024;   // wave-uniform, linear dest
        int m = half * 64 + l;
        int srcc = m ^ (r & 7);                       // inverse swizzle on source
        const char* gp = (const char*)hw + (((size_t)(r0 + r) << 10) + srcc * 8) * 2;
        __builtin_amdgcn_global_load_lds(gp, ldsb, 16, 0, 0);
      }
    }
    __syncthreads();                     // all staging landed
  }

  // ---- projection + softmax: slot-0 block of each XCD ----
  if (j == 0) {
    if (tid < 320) {
      int r = tid / 10;
      int cls = tid - r * 10;
      float acc = bp[cls];
      for (int k16 = 0; k16 < 128; ++k16) {
        const unsigned short* hp =
            (const unsigned short*)(hls + r * 2048 + ((k16 * 16) ^ ((r & 7) << 4)));
        #pragma unroll
        for (int e = 0; e < 8; ++e) acc += bf2f(hp[e]) * wph[(k16 * 8 + e) * Cc + cls];
      }
      zbuf[r * 16 + cls] = acc;
    }
    __syncthreads();
    if (tid < 32) {
      int r = tid;
      float m = -1e30f;
      #pragma unroll
      for (int cc = 0; cc < Cc; ++cc) m = fmaxf(m, zbuf[r * 16 + cc]);
      float s = 0.f;
      float ev[Cc];
      #pragma unroll
      for (int cc = 0; cc < Cc; ++cc) { ev[cc] = __expf(zbuf[r * 16 + cc] - m); s += ev[cc]; }
      float inv = 1.0f / s;
      #pragma unroll
      for (int cc = 0; cc < Cc; ++cc) out[(r0 + r) * Cc + cc] = ev[cc] * inv;
    }
  }
}

extern "C" void kernel_launch(void* const* d_in, const int* in_sizes, int n_in,
                              void* d_out, int out_size, void* d_ws, size_t ws_size,
                              hipStream_t stream) {
  const float* x   = (const float*)d_in[0];
  const float* wgx = (const float*)d_in[1];
  const float* wgh = (const float*)d_in[2];
  const float* bg  = (const float*)d_in[3];
  const float* wix = (const float*)d_in[4];
  const float* wih = (const float*)d_in[5];
  const float* bi  = (const float*)d_in[6];
  const float* wfx = (const float*)d_in[7];
  const float* wfh = (const float*)d_in[8];
  const float* bfp = (const float*)d_in[9];
  const float* wox = (const float*)d_in[10];
  const float* woh = (const float*)d_in[11];
  const float* bo  = (const float*)d_in[12];
  const float* wph = (const float*)d_in[13];
  const float* bp  = (const float*)d_in[14];
  float* out = (float*)d_out;

  unsigned short* hbuf = (unsigned short*)d_ws;                     // 2 x 512KB
  unsigned* sync = (unsigned*)((char*)d_ws + (size_t)2 * HBELT * 2);
  // sync layout (u32): flags 8*32*32 | epochs 8*8*32 | cnt 8

  hipMemsetAsync(sync, 0, (8 * 32 * 32 + 8 * 8 * 32 + 8) * sizeof(unsigned), stream);

  size_t shmem = 65536 + 16384 + 65536 + 1024;
  hipFuncSetAttribute((const void*)lstm_kernel,
                      hipFuncAttributeMaxDynamicSharedMemorySize, (int)shmem);

  void* args[] = {
    (void*)&x,   (void*)&wgx, (void*)&wgh, (void*)&bg,
    (void*)&wix, (void*)&wih, (void*)&bi,
    (void*)&wfx, (void*)&wfh, (void*)&bfp,
    (void*)&wox, (void*)&woh, (void*)&bo,
    (void*)&wph, (void*)&bp,
    (void*)&out, (void*)&hbuf, (void*)&sync
  };
  hipLaunchCooperativeKernel((const void*)lstm_kernel, dim3(256), dim3(512),
                             args, (unsigned)shmem, stream);
}

// Round 8
// 5736.264 us; speedup vs baseline: 4.4399x; 1.5031x over previous
//
#include <hip/hip_runtime.h>

#define Tt  512
#define Hd  1024
#define Cc  10
#define HBHALF (256 * 1024)   // elements per h buffer [256][1024]

typedef short bf16x8 __attribute__((ext_vector_type(8)));
typedef float f32x4 __attribute__((ext_vector_type(4)));

__device__ __forceinline__ unsigned short f2bf(float f) {
  unsigned u = __builtin_bit_cast(unsigned, f);
  u = (u + 0x7FFFu + ((u >> 16) & 1u)) >> 16;   // RTNE
  return (unsigned short)u;
}
__device__ __forceinline__ float bf2f(unsigned short s) {
  unsigned u = ((unsigned)s) << 16;
  return __builtin_bit_cast(float, u);
}
__device__ __forceinline__ float sigmf_(float z) { return 1.0f / (1.0f + __expf(-z)); }
__device__ __forceinline__ float tanhf_(float z) { return 1.0f - 2.0f / (__expf(2.0f * z) + 1.0f); }

// ---- prep: fuse+transpose Wh (f32 [k][col]) -> whT (bf16 [gate][col][k]) ----
__global__ __launch_bounds__(256) void lstm_prep(
    const float* __restrict__ wgh, const float* __restrict__ wih,
    const float* __restrict__ wfh, const float* __restrict__ woh,
    unsigned short* __restrict__ whT)
{
  __shared__ float tile[64][65];
  const int bid = blockIdx.x;
  const int q  = bid >> 8;          // gate
  const int ct = (bid >> 4) & 15;   // col tile (64)
  const int kt = bid & 15;          // k tile (64)
  const float* w = (q == 0) ? wgh : (q == 1) ? wih : (q == 2) ? wfh : woh;
  const int tid = threadIdx.x;
  const int tc = tid & 63, tr = tid >> 6;
  #pragma unroll
  for (int i = 0; i < 16; ++i) {
    int kk = i * 4 + tr;
    tile[kk][tc] = w[(size_t)(kt * 64 + kk) * Hd + ct * 64 + tc];
  }
  __syncthreads();
  #pragma unroll
  for (int i = 0; i < 16; ++i) {
    int cc = i * 4 + tr;
    whT[(size_t)(q * 1024 + ct * 64 + cc) * Hd + kt * 64 + tc] = f2bf(tile[tc][cc]);
  }
}

// ---- one timestep: z = h@Wh (MFMA) + gates + c/h update, fused ----
__global__ __launch_bounds__(256) void lstm_step(
    const unsigned short* __restrict__ whT,
    const float* __restrict__ x,
    const float* __restrict__ wgx, const float* __restrict__ wix,
    const float* __restrict__ wfx, const float* __restrict__ wox,
    const float* __restrict__ bg,  const float* __restrict__ bi,
    const float* __restrict__ bfp, const float* __restrict__ bo,
    const unsigned short* __restrict__ hR,   // h_t   [256][1024] bf16
    unsigned short* __restrict__ hW,         // h_t+1 [256][1024] bf16
    float* __restrict__ cbuf,                // c     [256][1024] f32
    int t)
{
  extern __shared__ char smem[];
  char*  hls  = smem;                        // [32 rows][2048B] swizzled bf16, 64KB
  float* zbuf = (float*)(smem + 65536);      // [32][128] f32, 16KB

  const int tid = threadIdx.x;
  const int l   = tid & 63;
  const int w4  = tid >> 6;        // wave 0..3 == gate q
  const int cb  = blockIdx.x & 31; // col block  (cb%8 -> XCD round-robin heuristic)
  const int rg  = blockIdx.x >> 5; // row group
  const int r0  = rg * 32;
  const int hc0 = cb * 32;

  // ---- stage h rows [r0, r0+32) -> LDS (pre-swizzled global source) ----
  {
    int rbase = w4 * 8;
    #pragma unroll
    for (int i = 0; i < 16; ++i) {
      int r = rbase + (i >> 1);
      int half = i & 1;
      char* ldsb = hls + r * 2048 + half * 1024;    // wave-uniform, linear dest
      int m = half * 64 + l;                         // dest 16B-chunk index
      int srcc = m ^ (r & 7);                        // inverse swizzle on source
      const char* gp = (const char*)hR + (((size_t)(r0 + r) << 10) + srcc * 8) * 2;
      __builtin_amdgcn_global_load_lds(gp, ldsb, 16, 0, 0);
    }
  }
  __syncthreads();

  // ---- z-tile: 32 rows x 32 cols for gate q; B streamed from whT (L2) ----
  const int q   = w4;
  const int lc  = l & 15;
  const int kb8 = (l >> 4) * 8;              // k sub-chunk (elements)
  const int roff0 = lc * 2048;
  const int roff1 = roff0 + 16 * 2048;
  const int swz   = (l & 7) << 4;
  const int kboff = (l >> 4) * 16;           // byte offset within row
  const unsigned short* wcol0 = whT + (size_t)(q * 1024 + hc0 + lc) * Hd + kb8;
  const unsigned short* wcol1 = wcol0 + (size_t)16 * Hd;

  f32x4 acc00 = {0.f,0.f,0.f,0.f};
  f32x4 acc01 = {0.f,0.f,0.f,0.f};
  f32x4 acc10 = {0.f,0.f,0.f,0.f};
  f32x4 acc11 = {0.f,0.f,0.f,0.f};
  #pragma unroll
  for (int kc = 0; kc < 32; ++kc) {
    int boff = (kc * 64 + kboff) ^ swz;
    bf16x8 a0 = *(const bf16x8*)(hls + roff0 + boff);
    bf16x8 a1 = *(const bf16x8*)(hls + roff1 + boff);
    bf16x8 b0 = *(const bf16x8*)(wcol0 + kc * 32);
    bf16x8 b1 = *(const bf16x8*)(wcol1 + kc * 32);
    acc00 = __builtin_amdgcn_mfma_f32_16x16x32_bf16(a0, b0, acc00, 0, 0, 0);
    acc01 = __builtin_amdgcn_mfma_f32_16x16x32_bf16(a0, b1, acc01, 0, 0, 0);
    acc10 = __builtin_amdgcn_mfma_f32_16x16x32_bf16(a1, b0, acc10, 0, 0, 0);
    acc11 = __builtin_amdgcn_mfma_f32_16x16x32_bf16(a1, b1, acc11, 0, 0, 0);
  }

  // ---- acc -> zbuf (C/D layout: col = l&15, row = (l>>4)*4 + p) ----
  {
    int colz = q * 32 + lc;
    int rb = (l >> 4) * 4;
    #pragma unroll
    for (int p = 0; p < 4; ++p) {
      zbuf[(rb + p) * 128 + colz]           = acc00[p];
      zbuf[(rb + p) * 128 + colz + 16]      = acc01[p];
      zbuf[(rb + p + 16) * 128 + colz]      = acc10[p];
      zbuf[(rb + p + 16) * 128 + colz + 16] = acc11[p];
    }
  }
  __syncthreads();

  // ---- gates + c update (f32), write h' and c ----
  #pragma unroll
  for (int e = 0; e < 4; ++e) {
    int idx = tid + e * 256;
    int r = idx >> 5, hc = idx & 31;
    int hcol = hc0 + hc;
    float xv = x[(size_t)(r0 + r) * Tt + t];
    float zg = zbuf[r * 128 +       hc] + xv * wgx[hcol] + bg[hcol];
    float zi = zbuf[r * 128 +  32 + hc] + xv * wix[hcol] + bi[hcol];
    float zf = zbuf[r * 128 +  64 + hc] + xv * wfx[hcol] + bfp[hcol];
    float zo = zbuf[r * 128 +  96 + hc] + xv * wox[hcol] + bo[hcol];
    float G = tanhf_(zg);
    float I = sigmf_(zi);
    float F = sigmf_(zf);
    float O = sigmf_(zo);
    size_t ci = (size_t)(r0 + r) * Hd + hcol;
    float cnew = G * I + cbuf[ci] * F;
    cbuf[ci] = cnew;
    hW[ci] = f2bf(tanhf_(cnew) * O);
  }
}

// ---- projection + softmax ----
__global__ __launch_bounds__(256) void lstm_final(
    const unsigned short* __restrict__ h, const float* __restrict__ wph,
    const float* __restrict__ bp, float* __restrict__ out)
{
  __shared__ float zrow[16][10];
  const int tid = threadIdx.x;
  if (tid < 160) {
    int rr = tid / 10, c = tid - rr * 10;
    int r = blockIdx.x * 16 + rr;
    float acc = bp[c];
    for (int k = 0; k < Hd; ++k) acc += bf2f(h[(size_t)r * Hd + k]) * wph[k * Cc + c];
    zrow[rr][c] = acc;
  }
  __syncthreads();
  if (tid < 16) {
    int r = blockIdx.x * 16 + tid;
    float m = -1e30f;
    #pragma unroll
    for (int cc = 0; cc < Cc; ++cc) m = fmaxf(m, zrow[tid][cc]);
    float s = 0.f;
    float ev[Cc];
    #pragma unroll
    for (int cc = 0; cc < Cc; ++cc) { ev[cc] = __expf(zrow[tid][cc] - m); s += ev[cc]; }
    float inv = 1.0f / s;
    #pragma unroll
    for (int cc = 0; cc < Cc; ++cc) out[r * Cc + cc] = ev[cc] * inv;
  }
}

extern "C" void kernel_launch(void* const* d_in, const int* in_sizes, int n_in,
                              void* d_out, int out_size, void* d_ws, size_t ws_size,
                              hipStream_t stream) {
  const float* x   = (const float*)d_in[0];
  const float* wgx = (const float*)d_in[1];
  const float* wgh = (const float*)d_in[2];
  const float* bg  = (const float*)d_in[3];
  const float* wix = (const float*)d_in[4];
  const float* wih = (const float*)d_in[5];
  const float* bi  = (const float*)d_in[6];
  const float* wfx = (const float*)d_in[7];
  const float* wfh = (const float*)d_in[8];
  const float* bfp = (const float*)d_in[9];
  const float* wox = (const float*)d_in[10];
  const float* woh = (const float*)d_in[11];
  const float* bo  = (const float*)d_in[12];
  const float* wph = (const float*)d_in[13];
  const float* bp  = (const float*)d_in[14];
  float* out = (float*)d_out;

  // d_ws layout: whT 8.0MB | hbuf 2x512KB | cbuf 1MB   (total ~10MB)
  unsigned short* whT  = (unsigned short*)d_ws;
  unsigned short* hbuf = (unsigned short*)((char*)d_ws + (size_t)4 * 1024 * Hd * 2);
  float* cbuf = (float*)((char*)hbuf + (size_t)2 * HBHALF * 2);

  hipMemsetAsync(hbuf, 0, (size_t)HBHALF * 2, stream);       // h_0 = 0
  hipMemsetAsync(cbuf, 0, (size_t)HBHALF * 4, stream);       // c_0 = 0

  hipFuncSetAttribute((const void*)lstm_step,
                      hipFuncAttributeMaxDynamicSharedMemorySize, 81920);

  lstm_prep<<<1024, 256, 0, stream>>>(wgh, wih, wfh, woh, whT);

  for (int t = 0; t < Tt; ++t) {
    const unsigned short* hR = hbuf + (size_t)(t & 1) * HBHALF;
    unsigned short*       hW = hbuf + (size_t)((t + 1) & 1) * HBHALF;
    lstm_step<<<256, 256, 81920, stream>>>(whT, x, wgx, wix, wfx, wox,
                                           bg, bi, bfp, bo, hR, hW, cbuf, t);
  }

  lstm_final<<<16, 256, 0, stream>>>(hbuf /* parity 0 = h_T */, wph, bp, out);
}

// Round 9
// 5591.572 us; speedup vs baseline: 4.5548x; 1.0259x over previous
//
#include <hip/hip_runtime.h>

#define Tt  512
#define Hd  1024
#define Cc  10
#define HBHALF (256 * 1024)   // elements per h buffer [256][1024]

typedef short bf16x8 __attribute__((ext_vector_type(8)));
typedef float f32x4 __attribute__((ext_vector_type(4)));

__device__ __forceinline__ unsigned short f2bf(float f) {
  unsigned u = __builtin_bit_cast(unsigned, f);
  u = (u + 0x7FFFu + ((u >> 16) & 1u)) >> 16;   // RTNE
  return (unsigned short)u;
}
__device__ __forceinline__ float bf2f(unsigned short s) {
  unsigned u = ((unsigned)s) << 16;
  return __builtin_bit_cast(float, u);
}
__device__ __forceinline__ float sigmf_(float z) { return 1.0f / (1.0f + __expf(-z)); }
__device__ __forceinline__ float tanhf_(float z) { return 1.0f - 2.0f / (__expf(2.0f * z) + 1.0f); }

// ---- prep: fuse+transpose Wh (f32 [k][col]) -> whT (bf16 [gate][col][k]) ----
__global__ __launch_bounds__(256) void lstm_prep(
    const float* __restrict__ wgh, const float* __restrict__ wih,
    const float* __restrict__ wfh, const float* __restrict__ woh,
    unsigned short* __restrict__ whT)
{
  __shared__ float tile[64][65];
  const int bid = blockIdx.x;
  const int q  = bid >> 8;          // gate
  const int ct = (bid >> 4) & 15;   // col tile (64)
  const int kt = bid & 15;          // k tile (64)
  const float* w = (q == 0) ? wgh : (q == 1) ? wih : (q == 2) ? wfh : woh;
  const int tid = threadIdx.x;
  const int tc = tid & 63, tr = tid >> 6;
  #pragma unroll
  for (int i = 0; i < 16; ++i) {
    int kk = i * 4 + tr;
    tile[kk][tc] = w[(size_t)(kt * 64 + kk) * Hd + ct * 64 + tc];
  }
  __syncthreads();
  #pragma unroll
  for (int i = 0; i < 16; ++i) {
    int cc = i * 4 + tr;
    whT[(size_t)(q * 1024 + ct * 64 + cc) * Hd + kt * 64 + tc] = f2bf(tile[tc][cc]);
  }
}

// ---- one timestep: z = h@Wh (MFMA) + gates + c/h update, fused ----
// 512 threads = 8 waves = 2 waves/SIMD (latency hiding for B-streaming).
__global__ __launch_bounds__(512) void lstm_step(
    const unsigned short* __restrict__ whT,
    const float* __restrict__ x,
    const float* __restrict__ wgx, const float* __restrict__ wix,
    const float* __restrict__ wfx, const float* __restrict__ wox,
    const float* __restrict__ bg,  const float* __restrict__ bi,
    const float* __restrict__ bfp, const float* __restrict__ bo,
    const unsigned short* __restrict__ hR,   // h_t   [256][1024] bf16
    unsigned short* __restrict__ hW,         // h_t+1 [256][1024] bf16
    float* __restrict__ cbuf,                // c     [256][1024] f32
    int t)
{
  extern __shared__ char smem[];
  char*  hls  = smem;                        // [32 rows][2048B] swizzled bf16, 64KB
  float* zbuf = (float*)(smem + 65536);      // [32][128] f32, 16KB
  __shared__ float xsh[32];

  const int tid = threadIdx.x;
  const int l   = tid & 63;
  const int w   = tid >> 6;        // wave 0..7
  const int cb  = blockIdx.x & 31; // col block (round-robins over XCDs)
  const int rg  = blockIdx.x >> 5; // row group
  const int r0  = rg * 32;
  const int hc0 = cb * 32;

  // ---- x broadcast values (overlaps with staging) ----
  if (tid < 32) xsh[tid] = x[(size_t)(r0 + tid) * Tt + t];

  // ---- stage h rows [r0, r0+32) -> LDS (pre-swizzled global source) ----
  {
    int rbase = w * 4;
    #pragma unroll
    for (int i = 0; i < 8; ++i) {
      int r = rbase + (i >> 1);
      int half = i & 1;
      char* ldsb = hls + r * 2048 + half * 1024;    // wave-uniform, linear dest
      int m = half * 64 + l;                         // dest 16B-chunk index
      int srcc = m ^ (r & 7);                        // inverse swizzle on source
      const char* gp = (const char*)hR + (((size_t)(r0 + r) << 10) + srcc * 8) * 2;
      __builtin_amdgcn_global_load_lds(gp, ldsb, 16, 0, 0);
    }
  }
  __syncthreads();

  // ---- z-tile: wave w -> gate q = w>>1, 16 cols at (w&1)*16 ----
  const int q  = w >> 1;
  const int lc = l & 15;
  const int roff0 = lc * 2048;
  const int roff1 = roff0 + 16 * 2048;
  const int swz   = (l & 7) << 4;
  const int kboff = (l >> 4) * 16;           // byte offset of k sub-chunk
  const unsigned short* wcol =
      whT + (size_t)(q * 1024 + hc0 + ((w & 1) << 4) + lc) * Hd + (l >> 4) * 8;

  f32x4 acc0 = {0.f,0.f,0.f,0.f};
  f32x4 acc1 = {0.f,0.f,0.f,0.f};
  #pragma unroll
  for (int kc = 0; kc < 32; ++kc) {
    int boff = (kc * 64 + kboff) ^ swz;
    bf16x8 a0 = *(const bf16x8*)(hls + roff0 + boff);
    bf16x8 a1 = *(const bf16x8*)(hls + roff1 + boff);
    bf16x8 b  = *(const bf16x8*)(wcol + kc * 32);
    acc0 = __builtin_amdgcn_mfma_f32_16x16x32_bf16(a0, b, acc0, 0, 0, 0);
    acc1 = __builtin_amdgcn_mfma_f32_16x16x32_bf16(a1, b, acc1, 0, 0, 0);
  }

  // ---- acc -> zbuf (C/D layout: col = l&15, row = (l>>4)*4 + p) ----
  {
    int colz  = (w << 4) + lc;               // fused col: q*32 + (w&1)*16 + lc
    int rbase = (l >> 4) * 4;
    #pragma unroll
    for (int p = 0; p < 4; ++p) {
      zbuf[(rbase + p) * 128 + colz]      = acc0[p];
      zbuf[(rbase + p + 16) * 128 + colz] = acc1[p];
    }
  }
  __syncthreads();

  // ---- gates + c update (f32), write h' and c ----
  #pragma unroll
  for (int e = 0; e < 2; ++e) {
    int idx = tid + e * 512;
    int r = idx >> 5, hc = idx & 31;
    int hcol = hc0 + hc;
    float xv = xsh[r];
    float zg = zbuf[r * 128 +       hc] + xv * wgx[hcol] + bg[hcol];
    float zi = zbuf[r * 128 +  32 + hc] + xv * wix[hcol] + bi[hcol];
    float zf = zbuf[r * 128 +  64 + hc] + xv * wfx[hcol] + bfp[hcol];
    float zo = zbuf[r * 128 +  96 + hc] + xv * wox[hcol] + bo[hcol];
    float G = tanhf_(zg);
    float I = sigmf_(zi);
    float F = sigmf_(zf);
    float O = sigmf_(zo);
    size_t ci = (size_t)(r0 + r) * Hd + hcol;
    float cnew = G * I + cbuf[ci] * F;
    cbuf[ci] = cnew;
    hW[ci] = f2bf(tanhf_(cnew) * O);
  }
}

// ---- projection + softmax ----
__global__ __launch_bounds__(256) void lstm_final(
    const unsigned short* __restrict__ h, const float* __restrict__ wph,
    const float* __restrict__ bp, float* __restrict__ out)
{
  __shared__ float zrow[16][10];
  const int tid = threadIdx.x;
  if (tid < 160) {
    int rr = tid / 10, c = tid - rr * 10;
    int r = blockIdx.x * 16 + rr;
    float acc = bp[c];
    for (int k8 = 0; k8 < 128; ++k8) {
      bf16x8 hv = *(const bf16x8*)(h + (size_t)r * Hd + k8 * 8);
      #pragma unroll
      for (int e = 0; e < 8; ++e)
        acc += bf2f((unsigned short)hv[e]) * wph[(k8 * 8 + e) * Cc + c];
    }
    zrow[rr][c] = acc;
  }
  __syncthreads();
  if (tid < 16) {
    int r = blockIdx.x * 16 + tid;
    float m = -1e30f;
    #pragma unroll
    for (int cc = 0; cc < Cc; ++cc) m = fmaxf(m, zrow[tid][cc]);
    float s = 0.f;
    float ev[Cc];
    #pragma unroll
    for (int cc = 0; cc < Cc; ++cc) { ev[cc] = __expf(zrow[tid][cc] - m); s += ev[cc]; }
    float inv = 1.0f / s;
    #pragma unroll
    for (int cc = 0; cc < Cc; ++cc) out[r * Cc + cc] = ev[cc] * inv;
  }
}

extern "C" void kernel_launch(void* const* d_in, const int* in_sizes, int n_in,
                              void* d_out, int out_size, void* d_ws, size_t ws_size,
                              hipStream_t stream) {
  const float* x   = (const float*)d_in[0];
  const float* wgx = (const float*)d_in[1];
  const float* wgh = (const float*)d_in[2];
  const float* bg  = (const float*)d_in[3];
  const float* wix = (const float*)d_in[4];
  const float* wih = (const float*)d_in[5];
  const float* bi  = (const float*)d_in[6];
  const float* wfx = (const float*)d_in[7];
  const float* wfh = (const float*)d_in[8];
  const float* bfp = (const float*)d_in[9];
  const float* wox = (const float*)d_in[10];
  const float* woh = (const float*)d_in[11];
  const float* bo  = (const float*)d_in[12];
  const float* wph = (const float*)d_in[13];
  const float* bp  = (const float*)d_in[14];
  float* out = (float*)d_out;

  // d_ws layout: whT 8.0MB | hbuf 2x512KB | cbuf 1MB
  unsigned short* whT  = (unsigned short*)d_ws;
  unsigned short* hbuf = (unsigned short*)((char*)d_ws + (size_t)4 * 1024 * Hd * 2);
  float* cbuf = (float*)((char*)hbuf + (size_t)2 * HBHALF * 2);

  hipMemsetAsync(hbuf, 0, (size_t)HBHALF * 2, stream);       // h_0 = 0
  hipMemsetAsync(cbuf, 0, (size_t)HBHALF * 4, stream);       // c_0 = 0

  hipFuncSetAttribute((const void*)lstm_step,
                      hipFuncAttributeMaxDynamicSharedMemorySize, 81920);

  lstm_prep<<<1024, 256, 0, stream>>>(wgh, wih, wfh, woh, whT);

  for (int t = 0; t < Tt; ++t) {
    const unsigned short* hR = hbuf + (size_t)(t & 1) * HBHALF;
    unsigned short*       hW = hbuf + (size_t)((t + 1) & 1) * HBHALF;
    lstm_step<<<256, 512, 81920, stream>>>(whT, x, wgx, wix, wfx, wox,
                                           bg, bi, bfp, bo, hR, hW, cbuf, t);
  }

  lstm_final<<<16, 256, 0, stream>>>(hbuf /* parity 0 = h_T */, wph, bp, out);
}